// Round 5
// baseline (120.468 us; speedup 1.0000x reference)
//
#include <hip/hip_runtime.h>
#include <hip/hip_bf16.h>
#include <math.h>

// Problem constants
#define B_    4
#define C_IN_ 128
#define N_    2048
#define NSEL_ 1024
#define H_    4
#define KS_   4            // key-split chunks (512 keys = 8 tiles of 64 each)

typedef __bf16 bf16;
typedef __bf16 bf16x2 __attribute__((ext_vector_type(2)));
typedef __bf16 bf16x4 __attribute__((ext_vector_type(4)));
typedef __bf16 bf16x8 __attribute__((ext_vector_type(8)));
typedef float  f32x4  __attribute__((ext_vector_type(4)));

// async global->LDS, 16B per lane; LDS dest is wave-uniform base + lane*16
__device__ __forceinline__ void gll16(const void* g, void* l) {
    __builtin_amdgcn_global_load_lds((const __attribute__((address_space(1))) void*)g,
                                     (__attribute__((address_space(3))) void*)l,
                                     16, 0, 0);
}

__device__ __forceinline__ bf16x8 cvt8(float4 a, float4 b) {
    bf16x8 r;
    r[0] = (bf16)a.x; r[1] = (bf16)a.y; r[2] = (bf16)a.z; r[3] = (bf16)a.w;
    r[4] = (bf16)b.x; r[5] = (bf16)b.y; r[6] = (bf16)b.z; r[7] = (bf16)b.w;
    return r;
}

// native 2^x (avoid ocml fixup path)
__device__ __forceinline__ float fast_exp2(float x) {
#if __has_builtin(__builtin_amdgcn_exp2f)
    return __builtin_amdgcn_exp2f(x);
#else
    return exp2f(x);
#endif
}

// ---------------------------------------------------------------------------
// Kernel 1: Q/K/V MFMA GEMM (grid (32, 6, B): which = y>>1 in {0,1,2}).
// Prep kernel folded in: inv perm written by y==0 blocks; W read fp32 + cvt.
// Q pre-scaled by 0.125*log2(e) so attention can use exp2.
// K/V tiles stored PRE-SWIZZLED in global (col ^= ((row&7)<<3)) so attention
// can global_load_lds them linearly and read with the same XOR.
//   qT : (bh, n, 64) bf16
//   kTt: (bh, tile, key&63, d^swz) 8KB tiles
//   vTt: (bh, tile, dv, slot'^swz) 8KB tiles; slot' = (key&15)*4 + (key>>4)
// ---------------------------------------------------------------------------
#define XSTR 136

__global__ __launch_bounds__(256) void qkv_mfma_kernel(
    const float* __restrict__ sel, const float* __restrict__ drop,
    const float* __restrict__ Wq, const float* __restrict__ Wk,
    const float* __restrict__ Wv,
    const int* __restrict__ isel, const int* __restrict__ idrp,
    int* __restrict__ inv,
    bf16* __restrict__ qT, bf16* __restrict__ kTt, bf16* __restrict__ vTt)
{
    const int ntile = blockIdx.x;
    const int which = blockIdx.y >> 1;   // 0=Q 1=K 2=V
    const int rh    = blockIdx.y & 1;    // 128-row half
    const int b     = blockIdx.z;
    const int tid   = threadIdx.x;
    const int w     = tid >> 6;
    const int lane  = tid & 63;
    const int quad  = lane >> 4;
    const int lc    = lane & 15;
    const int n0    = ntile * 64;

    __shared__ __align__(16) bf16 xT[64 * XSTR];

    // folded prep: inverse permutation (8 blocks per b suffice: 8*256 = 2048)
    if (blockIdx.y == 0 && ntile < 8) {
        int j = ntile * 256 + tid;
        int pos = (j < NSEL_) ? isel[b * NSEL_ + j] : idrp[b * NSEL_ + (j - NSEL_)];
        inv[b * N_ + (pos & (N_ - 1))] = j;
    }

    const float* srcp; int rstride;
    if (ntile < 16) { srcp = sel  + (size_t)b * C_IN_ * NSEL_ + n0;           rstride = NSEL_; }
    else            { srcp = drop + (size_t)b * C_IN_ * NSEL_ + (n0 - NSEL_); rstride = NSEL_; }

    // Stage x fp32 [c][n] -> bf16 xT [n][c ^ swz]; swz = ((n>>2)&3)<<3.
    #pragma unroll
    for (int k = 0; k < 4; ++k) {
        int e  = tid + k * 256;          // 0..1023
        int cp = e >> 4, nq = e & 15;
        int c0 = cp * 2;
        float4 v0 = *(const float4*)(srcp + (size_t)c0 * rstride + nq * 4);
        float4 v1 = *(const float4*)(srcp + (size_t)(c0 + 1) * rstride + nq * 4);
        int cc = c0 ^ ((nq & 3) << 3);
        float a0[4] = {v0.x, v0.y, v0.z, v0.w};
        float a1[4] = {v1.x, v1.y, v1.z, v1.w};
        #pragma unroll
        for (int i = 0; i < 4; ++i) {
            int n = nq * 4 + i;
            bf16x2 t; t[0] = (bf16)a0[i]; t[1] = (bf16)a1[i];
            *(bf16x2*)&xT[n * XSTR + cc] = t;
        }
    }
    __syncthreads();

    const float* Wx = (which == 0) ? Wq : (which == 1) ? Wk : Wv;
    const int rbase = rh * 128 + w * 32;

    f32x4 acc[8];
    #pragma unroll
    for (int i = 0; i < 8; ++i) acc[i] = (f32x4){0.f, 0.f, 0.f, 0.f};

    #pragma unroll
    for (int kq = 0; kq < 4; ++kq) {
        bf16x8 wf[2], xA[4];
        #pragma unroll
        for (int ot = 0; ot < 2; ++ot) {
            const float* wp = Wx + (size_t)(rbase + ot * 16 + lc) * 128 + kq * 32 + quad * 8;
            float4 u0 = *(const float4*)wp;
            float4 u1 = *(const float4*)(wp + 4);
            wf[ot] = cvt8(u0, u1);
        }
        #pragma unroll
        for (int nt = 0; nt < 4; ++nt) {
            int row = nt * 16 + lc;
            int col = (kq * 32 + quad * 8) ^ (((row >> 2) & 3) << 3);
            xA[nt] = *(const bf16x8*)&xT[row * XSTR + col];
        }
        if (which <= 1) {   // swapped: A=x (m=n), B=W (col=o)
            #pragma unroll
            for (int nt = 0; nt < 4; ++nt)
                #pragma unroll
                for (int ot = 0; ot < 2; ++ot)
                    acc[nt * 2 + ot] = __builtin_amdgcn_mfma_f32_16x16x32_bf16(xA[nt], wf[ot], acc[nt * 2 + ot], 0, 0, 0);
        } else {            // V: A=W (m=o), B=x (col=n)
            #pragma unroll
            for (int ot = 0; ot < 2; ++ot)
                #pragma unroll
                for (int nt = 0; nt < 4; ++nt)
                    acc[ot * 4 + nt] = __builtin_amdgcn_mfma_f32_16x16x32_bf16(wf[ot], xA[nt], acc[ot * 4 + nt], 0, 0, 0);
        }
    }

    if (which <= 1) {
        // C: row=n-local (quad*4+r), col=o-local (lc) -> d-contiguous stores.
        #pragma unroll
        for (int nt = 0; nt < 4; ++nt) {
            #pragma unroll
            for (int ot = 0; ot < 2; ++ot) {
                #pragma unroll
                for (int r = 0; r < 4; ++r) {
                    int n    = n0 + nt * 16 + quad * 4 + r;
                    int rloc = nt * 16 + quad * 4 + r;
                    int o256 = rbase + ot * 16 + lc;
                    int h = o256 >> 6, d = o256 & 63;
                    float val = acc[nt * 2 + ot][r];
                    if (which == 0)
                        // 0.125 * log2(e): attention uses exp2
                        qT[((size_t)(b * H_ + h) * N_ + n) * 64 + d] = (bf16)(val * 0.18033688011f);
                    else
                        kTt[(((size_t)(b * H_ + h) * 32 + ntile) << 12) | (rloc << 6) | (d ^ ((rloc & 7) << 3))] = (bf16)val;
                }
            }
        }
    } else {
        // V: C row=o-local (quad*4+r), col=key-local (nt*16+lc).
        // Permuted slot' = lc*4 + nt -> b64 store; XOR-swizzled by dv.
        #pragma unroll
        for (int ot = 0; ot < 2; ++ot) {
            #pragma unroll
            for (int r = 0; r < 4; ++r) {
                int o256 = rbase + ot * 16 + quad * 4 + r;
                int h = o256 >> 6, dv = o256 & 63;
                bf16x4 pk;
                #pragma unroll
                for (int nt = 0; nt < 4; ++nt) pk[nt] = (bf16)acc[ot * 4 + nt][r];
                int scol = (lc * 4) ^ ((dv & 7) << 3);   // bits0-1 untouched: b64 aligned
                *(bf16x4*)(vTt + ((((size_t)(b * H_ + h) * 32 + ntile) << 12) | (dv << 6) | scol)) = pk;
            }
        }
    }
}

// ---------------------------------------------------------------------------
// Kernel 2: key-split flash attention. Block = 2 waves x 64 queries = 128 q.
// Grid 1024 = 4 blocks/CU: two INDEPENDENT blocks per SIMD-pair overlap each
// other's per-step barrier/vmcnt drains (same 8 waves/CU as before, but the
// barrier scope is halved and blocks are mutually async).
// t=4 q-tiles per wave. K/V double-buffered in LDS via global_load_lds
// (linear dest, pre-swizzled source); one __syncthreads per step.
// KS_=4 chunks of 512 keys -> 8 steps of 64 keys.
// grid 1024: id -> bh=id&15, qb=(id>>4)&15, c=id>>8.
// ---------------------------------------------------------------------------
#define PSTR 72

__global__ __launch_bounds__(128, 2) void attn_kernel(
    const bf16* __restrict__ qT, const bf16* __restrict__ kTt,
    const bf16* __restrict__ vTt, bf16* __restrict__ Opart,
    float* __restrict__ S_ws)
{
    const int id    = blockIdx.x;
    const int bh    = id & 15;
    const int qb    = (id >> 4) & 15;
    const int c     = id >> 8;           // 0..KS_-1
    const int b     = bh >> 2;
    const int h     = bh & 3;
    const int tid   = threadIdx.x;
    const int w     = tid >> 6;          // 0..1
    const int lane  = tid & 63;
    const int quad  = lane >> 4;
    const int lc    = lane & 15;
    const int n0    = qb * 128 + w * 64;

    __shared__ __align__(16) bf16 sK[2][64 * 64];
    __shared__ __align__(16) bf16 sV[2][64 * 64];
    __shared__ __align__(16) bf16 p_lds[2 * 16 * PSTR];
    bf16* pw = &p_lds[w * 16 * PSTR];

    const bf16* kbase = kTt + (((size_t)bh * 32 + c * 8) << 12);
    const bf16* vbase = vTt + (((size_t)bh * 32 + c * 8) << 12);

    // prologue: issue tile 0 -> buf 0 (each wave: 4KB of K + 4KB of V)
    #pragma unroll
    for (int j = 0; j < 4; ++j) {
        const int sseg = (w * 4 + j) << 9;          // 512-elem (1KB) segments
        gll16(kbase + sseg + lane * 8, &sK[0][sseg]);
        gll16(vbase + sseg + lane * 8, &sV[0][sseg]);
    }

    // Q fragments for 4 q-tiles (A layout)
    bf16x8 aq[4][2];
    #pragma unroll
    for (int t = 0; t < 4; ++t) {
        const bf16* qp = qT + ((size_t)bh * N_ + n0 + t * 16 + lc) * 64 + quad * 8;
        aq[t][0] = *(const bf16x8*)(qp);
        aq[t][1] = *(const bf16x8*)(qp + 32);
    }

    f32x4 accO[4][4];
    #pragma unroll
    for (int t = 0; t < 4; ++t)
        #pragma unroll
        for (int i = 0; i < 4; ++i) accO[t][i] = (f32x4){0.f, 0.f, 0.f, 0.f};
    float psum[4][4] = {{0.f,0.f,0.f,0.f},{0.f,0.f,0.f,0.f},
                        {0.f,0.f,0.f,0.f},{0.f,0.f,0.f,0.f}};

    const int rswz = (lc & 7) << 3;   // XOR swizzle matches producer layout

    for (int s = 0; s < 8; ++s) {
        const int buf = s & 1;
        // drains this wave's in-flight global_load_lds (vmcnt(0)) and joins
        // both waves: tile s fully resident in buf, everyone done with buf^1.
        __syncthreads();

        if (s < 7) {                   // prefetch tile s+1 into the other buf
            const bf16* kg = kbase + ((size_t)(s + 1) << 12);
            const bf16* vg = vbase + ((size_t)(s + 1) << 12);
            #pragma unroll
            for (int j = 0; j < 4; ++j) {
                const int sseg = (w * 4 + j) << 9;
                gll16(kg + sseg + lane * 8, &sK[buf ^ 1][sseg]);
                gll16(vg + sseg + lane * 8, &sV[buf ^ 1][sseg]);
            }
        }

        // fragments (shared by all 4 q-tiles)
        bf16x8 kf[4][2], vf[4][2];
        #pragma unroll
        for (int mt = 0; mt < 4; ++mt) {
            const int rb = (mt * 16 + lc) * 64;
            kf[mt][0] = *(const bf16x8*)&sK[buf][rb + ((quad * 8) ^ rswz)];
            kf[mt][1] = *(const bf16x8*)&sK[buf][rb + ((quad * 8 + 32) ^ rswz)];
            vf[mt][0] = *(const bf16x8*)&sV[buf][rb + ((quad * 8) ^ rswz)];
            vf[mt][1] = *(const bf16x8*)&sV[buf][rb + ((quad * 8 + 32) ^ rswz)];
        }

        #pragma unroll
        for (int t = 0; t < 4; ++t) {
            // ---- S ----
            f32x4 accS[4];
            #pragma unroll
            for (int mt = 0; mt < 4; ++mt) {
                f32x4 z = (f32x4){0.f, 0.f, 0.f, 0.f};
                z = __builtin_amdgcn_mfma_f32_16x16x32_bf16(aq[t][0], kf[mt][0], z, 0, 0, 0);
                z = __builtin_amdgcn_mfma_f32_16x16x32_bf16(aq[t][1], kf[mt][1], z, 0, 0, 0);
                accS[mt] = z;
            }
            // ---- P = exp2(S) (log2e folded into Q), per-lane partial sums ----
            #pragma unroll
            for (int r = 0; r < 4; ++r) {
                float sum = 0.f;
                #pragma unroll
                for (int mt = 0; mt < 4; ++mt) {
                    float p = fast_exp2(accS[mt][r]);
                    accS[mt][r] = p;
                    sum += p;
                }
                psum[t][r] += sum;
            }
            // ---- P -> LDS strip at permuted cols lc*4+mt: b64 writes ----
            #pragma unroll
            for (int r = 0; r < 4; ++r) {
                bf16x4 pk;
                #pragma unroll
                for (int mt = 0; mt < 4; ++mt) pk[mt] = (bf16)accS[mt][r];
                *(bf16x4*)&pw[(quad * 4 + r) * PSTR + lc * 4] = pk;
            }
            bf16x8 ap0 = *(const bf16x8*)(&pw[lc * PSTR + quad * 8]);
            bf16x8 ap1 = *(const bf16x8*)(&pw[lc * PSTR + 32 + quad * 8]);
            // ---- O += P * V^T (V pre-permuted to match) ----
            #pragma unroll
            for (int dvt = 0; dvt < 4; ++dvt) {
                accO[t][dvt] = __builtin_amdgcn_mfma_f32_16x16x32_bf16(ap0, vf[dvt][0], accO[t][dvt], 0, 0, 0);
                accO[t][dvt] = __builtin_amdgcn_mfma_f32_16x16x32_bf16(ap1, vf[dvt][1], accO[t][dvt], 0, 0, 0);
            }
        }
    }

    // ---- chunk denominators + chunk-normalized O ----
    #pragma unroll
    for (int t = 0; t < 4; ++t) {
        float inv_[4];
        #pragma unroll
        for (int r = 0; r < 4; ++r) {
            float s = psum[t][r];
            #pragma unroll
            for (int off = 1; off < 16; off <<= 1)
                s += __shfl_xor(s, off, 64);
            inv_[r] = 1.f / s;
            int n = n0 + t * 16 + quad * 4 + r;
            if (lc == 0)
                S_ws[((size_t)(c * B_ + b) * H_ + h) * N_ + n] = s;
        }
        #pragma unroll
        for (int r = 0; r < 4; ++r) {
            int n = n0 + t * 16 + quad * 4 + r;
            #pragma unroll
            for (int dvt = 0; dvt < 4; ++dvt) {
                int o = h * 64 + dvt * 16 + lc;
                Opart[((size_t)(c * B_ + b) * N_ + n) * 256 + o] = (bf16)(accO[t][dvt][r] * inv_[r]);
            }
        }
    }
}

// ---------------------------------------------------------------------------
// Kernel 3: skip GEMM (fp32 W inline cvt) + KS-chunk merge + permutation
// gather. Gather (inv -> S_ws/Opart) issued per-thread at kernel top so the
// dependent global round-trips overlap staging + GEMM.
// grid (32 pos-tiles, 4 og(=h), B), 256 thr.
// ---------------------------------------------------------------------------
__global__ __launch_bounds__(256) void scatter_kernel(
    const bf16* __restrict__ Opart, const float* __restrict__ S_ws,
    const int* __restrict__ inv, const float* __restrict__ pcd,
    const float* __restrict__ Ws, float* __restrict__ out)
{
    const int ptile = blockIdx.x;
    const int og    = blockIdx.y;     // == head h
    const int b     = blockIdx.z;
    const int tid   = threadIdx.x;
    const int w     = tid >> 6;
    const int lane  = tid & 63;
    const int quad  = lane >> 4;
    const int lc    = lane & 15;
    const int p0    = ptile * 64;

    __shared__ __align__(16) bf16 xT[64 * XSTR];    // pcd tile (dest order)
    __shared__ __align__(16) bf16 lds[64 * 72];     // merged attn [pos][o_loc]

    // --- early gather: issue the dependent inv -> S_ws/Opart chain now ---
    const int row0 = tid >> 3, seg = tid & 7, row1 = row0 + 32;
    int j0 = inv[b * N_ + p0 + row0] & (N_ - 1);
    int j1 = inv[b * N_ + p0 + row1] & (N_ - 1);
    float sv0[KS_], sv1[KS_];
    bf16x8 g0[KS_], g1[KS_];
    #pragma unroll
    for (int cc = 0; cc < KS_; ++cc) {
        g0[cc] = *(const bf16x8*)(Opart + (((size_t)(cc * B_ + b) * N_ + j0) << 8) + og * 64 + seg * 8);
        g1[cc] = *(const bf16x8*)(Opart + (((size_t)(cc * B_ + b) * N_ + j1) << 8) + og * 64 + seg * 8);
        sv0[cc] = S_ws[((size_t)(cc * B_ + b) * H_ + og) * N_ + j0];
        sv1[cc] = S_ws[((size_t)(cc * B_ + b) * H_ + og) * N_ + j1];
    }

    // stage pcd fp32 [c][pos] -> bf16 xT [pos][c^swz]
    const float* srcp = pcd + (size_t)b * C_IN_ * N_ + p0;
    #pragma unroll
    for (int k = 0; k < 4; ++k) {
        int e  = tid + k * 256;
        int cp = e >> 4, nq = e & 15;
        int c0 = cp * 2;
        float4 v0 = *(const float4*)(srcp + (size_t)c0 * N_ + nq * 4);
        float4 v1 = *(const float4*)(srcp + (size_t)(c0 + 1) * N_ + nq * 4);
        int cc = c0 ^ ((nq & 3) << 3);
        float a0[4] = {v0.x, v0.y, v0.z, v0.w};
        float a1[4] = {v1.x, v1.y, v1.z, v1.w};
        #pragma unroll
        for (int i = 0; i < 4; ++i) {
            int n = nq * 4 + i;
            bf16x2 t; t[0] = (bf16)a0[i]; t[1] = (bf16)a1[i];
            *(bf16x2*)&xT[n * XSTR + cc] = t;
        }
    }
    __syncthreads();

    // skip GEMM: rows og*64 + w*16 .. +15, cols p0..p0+63, K=128 (A=W fp32)
    f32x4 acc[4];
    #pragma unroll
    for (int i = 0; i < 4; ++i) acc[i] = (f32x4){0.f, 0.f, 0.f, 0.f};
    #pragma unroll
    for (int kq = 0; kq < 4; ++kq) {
        const float* wp = Ws + (size_t)(og * 64 + w * 16 + lc) * 128 + kq * 32 + quad * 8;
        float4 u0 = *(const float4*)wp;
        float4 u1 = *(const float4*)(wp + 4);
        bf16x8 A = cvt8(u0, u1);
        #pragma unroll
        for (int nt = 0; nt < 4; ++nt) {
            int row = nt * 16 + lc;
            int col = (kq * 32 + quad * 8) ^ (((row >> 2) & 3) << 3);
            bf16x8 Bf = *(const bf16x8*)&xT[row * XSTR + col];
            acc[nt] = __builtin_amdgcn_mfma_f32_16x16x32_bf16(A, Bf, acc[nt], 0, 0, 0);
        }
    }

    // merge KS chunks into lds[pos][o_loc] (gather data already in regs)
    {
        float d0 = 0.f, d1 = 0.f;
        #pragma unroll
        for (int cc = 0; cc < KS_; ++cc) { d0 += sv0[cc]; d1 += sv1[cc]; }
        float id0 = 1.f / d0, id1 = 1.f / d1;
        float a8[8], b8[8];
        #pragma unroll
        for (int i = 0; i < 8; ++i) { a8[i] = 0.f; b8[i] = 0.f; }
        #pragma unroll
        for (int cc = 0; cc < KS_; ++cc) {
            float w0 = sv0[cc] * id0, w1 = sv1[cc] * id1;
            #pragma unroll
            for (int i = 0; i < 8; ++i) {
                a8[i] += w0 * (float)g0[cc][i];
                b8[i] += w1 * (float)g1[cc][i];
            }
        }
        bf16x8 o8, p8;
        #pragma unroll
        for (int i = 0; i < 8; ++i) { o8[i] = (bf16)a8[i]; p8[i] = (bf16)b8[i]; }
        *(bf16x8*)&lds[row0 * 72 + seg * 8] = o8;
        *(bf16x8*)&lds[row1 * 72 + seg * 8] = p8;
    }
    __syncthreads();

    // combine: out = skip(acc) + lds[pos][o_loc]
    #pragma unroll
    for (int nt = 0; nt < 4; ++nt) {
        #pragma unroll
        for (int r = 0; r < 4; ++r) {
            int o_loc = w * 16 + quad * 4 + r;
            int p     = nt * 16 + lc;
            float attn = (float)lds[p * 72 + o_loc];
            out[((size_t)b * 256 + og * 64 + o_loc) * N_ + p0 + p] = acc[nt][r] + attn;
        }
    }
}

// ---------------------------------------------------------------------------
extern "C" void kernel_launch(void* const* d_in, const int* in_sizes, int n_in,
                              void* d_out, int out_size, void* d_ws, size_t ws_size,
                              hipStream_t stream) {
    const float* pcd  = (const float*)d_in[0];
    const float* sel  = (const float*)d_in[1];
    const float* drop = (const float*)d_in[2];
    const int*   isel = (const int*)d_in[3];
    const int*   idrp = (const int*)d_in[4];
    const float* Wq   = (const float*)d_in[5];
    const float* Wk   = (const float*)d_in[6];
    const float* Wv   = (const float*)d_in[7];
    const float* Ws   = (const float*)d_in[8];
    float* out = (float*)d_out;

    const size_t MB = 1024 * 1024;
    // ws: qT 4 | kTt 4 | vTt 4 | Opart 16 | S_ws 512K | inv 32K
    char*  ws    = (char*)d_ws;
    bf16*  qT    = (bf16*)(ws);
    bf16*  kTt   = (bf16*)(ws + 4 * MB);
    bf16*  vTt   = (bf16*)(ws + 8 * MB);
    bf16*  Opart = (bf16*)(ws + 12 * MB);
    float* S_ws  = (float*)(ws + 28 * MB);
    int*   inv   = (int*)(ws + 28 * MB + 512 * 1024);

    qkv_mfma_kernel<<<dim3(32, 6, B_), 256, 0, stream>>>(sel, drop, Wq, Wk, Wv,
                                                         isel, idrp, inv,
                                                         qT, kTt, vTt);
    attn_kernel<<<dim3(16 * 16 * KS_), 128, 0, stream>>>(qT, kTt, vTt, Opart, S_ws);
    scatter_kernel<<<dim3(32, 4, B_), 256, 0, stream>>>(Opart, S_ws, inv, pcd, Ws, out);
}

// Round 6
// 117.645 us; speedup vs baseline: 1.0240x; 1.0240x over previous
//
#include <hip/hip_runtime.h>
#include <hip/hip_bf16.h>
#include <math.h>

// Problem constants
#define B_    4
#define C_IN_ 128
#define N_    2048
#define NSEL_ 1024
#define H_    4
#define KS_   4            // key-split chunks (512 keys = 8 tiles of 64 each)

typedef __bf16 bf16;
typedef __bf16 bf16x2 __attribute__((ext_vector_type(2)));
typedef __bf16 bf16x4 __attribute__((ext_vector_type(4)));
typedef __bf16 bf16x8 __attribute__((ext_vector_type(8)));
typedef float  f32x4  __attribute__((ext_vector_type(4)));

// async global->LDS, 16B per lane; LDS dest is wave-uniform base + lane*16
__device__ __forceinline__ void gll16(const void* g, void* l) {
    __builtin_amdgcn_global_load_lds((const __attribute__((address_space(1))) void*)g,
                                     (__attribute__((address_space(3))) void*)l,
                                     16, 0, 0);
}

// native 2^x (avoid ocml fixup path)
__device__ __forceinline__ float fast_exp2(float x) {
#if __has_builtin(__builtin_amdgcn_exp2f)
    return __builtin_amdgcn_exp2f(x);
#else
    return exp2f(x);
#endif
}

// ---------------------------------------------------------------------------
// Kernel 0 (prep): W fp32 -> bf16 (Wbf, 4x256x128); inverse permutation.
// Kept as a separate launch: folding it into qkv (R2/R5) cost ~2.5 us by
// injecting fp32 W loads + cvts into qkv's inner loop.
// ---------------------------------------------------------------------------
__global__ __launch_bounds__(256) void prep_kernel(
    const int* __restrict__ isel, const int* __restrict__ idrp,
    const float* __restrict__ Wq, const float* __restrict__ Wk,
    const float* __restrict__ Wv, const float* __restrict__ Ws,
    int* __restrict__ inv, bf16* __restrict__ Wbf)
{
    const int blk = blockIdx.x;
    if (blk < 128) {
        int e = blk * 256 + threadIdx.x;
        int which = e >> 13, idx = e & 8191;
        const float* Wx = (which == 0) ? Wq : (which == 1) ? Wk
                        : (which == 2) ? Wv : Ws;
        float4 v = *(const float4*)(Wx + (size_t)idx * 4);
        bf16x4 o; o[0] = (bf16)v.x; o[1] = (bf16)v.y; o[2] = (bf16)v.z; o[3] = (bf16)v.w;
        *(bf16x4*)(Wbf + (size_t)which * 32768 + (size_t)idx * 4) = o;
    } else {
        int g = (blk - 128) * 256 + threadIdx.x;
        int b = g >> 11, j = g & (N_ - 1);
        int pos = (j < NSEL_) ? isel[b * NSEL_ + j] : idrp[b * NSEL_ + (j - NSEL_)];
        inv[b * N_ + (pos & (N_ - 1))] = j;
    }
}

// ---------------------------------------------------------------------------
// Kernel 1: Q/K/V MFMA GEMM (grid (32, 6, B): which = y>>1 in {0,1,2}).
// Q pre-scaled by 0.125*log2(e) so attention can use exp2.
// K/V tiles stored PRE-SWIZZLED in global (col ^= ((row&7)<<3)) so attention
// can global_load_lds them linearly and read with the same XOR.
//   qT : (bh, n, 64) bf16
//   kTt: (bh, tile, key&63, d^swz) 8KB tiles
//   vTt: (bh, tile, dv, slot'^swz) 8KB tiles; slot' = (key&15)*4 + (key>>4)
// ---------------------------------------------------------------------------
#define XSTR 136

__global__ __launch_bounds__(256) void qkv_mfma_kernel(
    const float* __restrict__ sel, const float* __restrict__ drop,
    const bf16* __restrict__ Wbf,
    bf16* __restrict__ qT, bf16* __restrict__ kTt, bf16* __restrict__ vTt)
{
    const int ntile = blockIdx.x;
    const int which = blockIdx.y >> 1;   // 0=Q 1=K 2=V
    const int rh    = blockIdx.y & 1;    // 128-row half
    const int b     = blockIdx.z;
    const int tid   = threadIdx.x;
    const int w     = tid >> 6;
    const int lane  = tid & 63;
    const int quad  = lane >> 4;
    const int lc    = lane & 15;
    const int n0    = ntile * 64;

    __shared__ __align__(16) bf16 xT[64 * XSTR];

    const float* srcp; int rstride;
    if (ntile < 16) { srcp = sel  + (size_t)b * C_IN_ * NSEL_ + n0;           rstride = NSEL_; }
    else            { srcp = drop + (size_t)b * C_IN_ * NSEL_ + (n0 - NSEL_); rstride = NSEL_; }

    // Stage x fp32 [c][n] -> bf16 xT [n][c ^ swz]; swz = ((n>>2)&3)<<3.
    #pragma unroll
    for (int k = 0; k < 4; ++k) {
        int e  = tid + k * 256;          // 0..1023
        int cp = e >> 4, nq = e & 15;
        int c0 = cp * 2;
        float4 v0 = *(const float4*)(srcp + (size_t)c0 * rstride + nq * 4);
        float4 v1 = *(const float4*)(srcp + (size_t)(c0 + 1) * rstride + nq * 4);
        int cc = c0 ^ ((nq & 3) << 3);
        float a0[4] = {v0.x, v0.y, v0.z, v0.w};
        float a1[4] = {v1.x, v1.y, v1.z, v1.w};
        #pragma unroll
        for (int i = 0; i < 4; ++i) {
            int n = nq * 4 + i;
            bf16x2 t; t[0] = (bf16)a0[i]; t[1] = (bf16)a1[i];
            *(bf16x2*)&xT[n * XSTR + cc] = t;
        }
    }
    __syncthreads();

    const bf16* wbase = Wbf + (size_t)which * 256 * 128;
    const int rbase = rh * 128 + w * 32;

    f32x4 acc[8];
    #pragma unroll
    for (int i = 0; i < 8; ++i) acc[i] = (f32x4){0.f, 0.f, 0.f, 0.f};

    #pragma unroll
    for (int kq = 0; kq < 4; ++kq) {
        bf16x8 wf[2], xA[4];
        #pragma unroll
        for (int ot = 0; ot < 2; ++ot)
            wf[ot] = *(const bf16x8*)(wbase + (size_t)(rbase + ot * 16 + lc) * 128 + kq * 32 + quad * 8);
        #pragma unroll
        for (int nt = 0; nt < 4; ++nt) {
            int row = nt * 16 + lc;
            int col = (kq * 32 + quad * 8) ^ (((row >> 2) & 3) << 3);
            xA[nt] = *(const bf16x8*)&xT[row * XSTR + col];
        }
        if (which <= 1) {   // swapped: A=x (m=n), B=W (col=o)
            #pragma unroll
            for (int nt = 0; nt < 4; ++nt)
                #pragma unroll
                for (int ot = 0; ot < 2; ++ot)
                    acc[nt * 2 + ot] = __builtin_amdgcn_mfma_f32_16x16x32_bf16(xA[nt], wf[ot], acc[nt * 2 + ot], 0, 0, 0);
        } else {            // V: A=W (m=o), B=x (col=n)
            #pragma unroll
            for (int ot = 0; ot < 2; ++ot)
                #pragma unroll
                for (int nt = 0; nt < 4; ++nt)
                    acc[ot * 4 + nt] = __builtin_amdgcn_mfma_f32_16x16x32_bf16(wf[ot], xA[nt], acc[ot * 4 + nt], 0, 0, 0);
        }
    }

    if (which <= 1) {
        // C: row=n-local (quad*4+r), col=o-local (lc) -> d-contiguous stores.
        #pragma unroll
        for (int nt = 0; nt < 4; ++nt) {
            #pragma unroll
            for (int ot = 0; ot < 2; ++ot) {
                #pragma unroll
                for (int r = 0; r < 4; ++r) {
                    int n    = n0 + nt * 16 + quad * 4 + r;
                    int rloc = nt * 16 + quad * 4 + r;
                    int o256 = rbase + ot * 16 + lc;
                    int h = o256 >> 6, d = o256 & 63;
                    float val = acc[nt * 2 + ot][r];
                    if (which == 0)
                        // 0.125 * log2(e): attention uses exp2
                        qT[((size_t)(b * H_ + h) * N_ + n) * 64 + d] = (bf16)(val * 0.18033688011f);
                    else
                        kTt[(((size_t)(b * H_ + h) * 32 + ntile) << 12) | (rloc << 6) | (d ^ ((rloc & 7) << 3))] = (bf16)val;
                }
            }
        }
    } else {
        // V: C row=o-local (quad*4+r), col=key-local (nt*16+lc).
        // Permuted slot' = lc*4 + nt -> b64 store; XOR-swizzled by dv.
        #pragma unroll
        for (int ot = 0; ot < 2; ++ot) {
            #pragma unroll
            for (int r = 0; r < 4; ++r) {
                int o256 = rbase + ot * 16 + quad * 4 + r;
                int h = o256 >> 6, dv = o256 & 63;
                bf16x4 pk;
                #pragma unroll
                for (int nt = 0; nt < 4; ++nt) pk[nt] = (bf16)acc[ot * 4 + nt][r];
                int scol = (lc * 4) ^ ((dv & 7) << 3);   // bits0-1 untouched: b64 aligned
                *(bf16x4*)(vTt + ((((size_t)(b * H_ + h) * 32 + ntile) << 12) | (dv << 6) | scol)) = pk;
            }
        }
    }
}

// ---------------------------------------------------------------------------
// Kernel 2: key-split flash attention. Block = 4 waves x 64 queries = 256 q.
// t=4 q-tiles per wave. K/V double-buffered in LDS via global_load_lds
// (linear dest, pre-swizzled source); one __syncthreads per step doubles as
// the vmcnt(0)+barrier drain. KS_=4 chunks of 512 keys -> 8 steps;
// grid 512 = 2 blocks/CU.
// grid 512: id -> bh=(id&7)+8*((id>>3)&1), qb=(id>>4)&7, c=id>>7 (XCD-aware).
// ---------------------------------------------------------------------------
#define PSTR 72

__global__ __launch_bounds__(256, 2) void attn_kernel(
    const bf16* __restrict__ qT, const bf16* __restrict__ kTt,
    const bf16* __restrict__ vTt, bf16* __restrict__ Opart,
    float* __restrict__ S_ws)
{
    const int id    = blockIdx.x;
    const int bh    = (id & 7) + 8 * ((id >> 3) & 1);
    const int qb    = (id >> 4) & 7;
    const int c     = id >> 7;           // 0..KS_-1
    const int b     = bh >> 2;
    const int h     = bh & 3;
    const int tid   = threadIdx.x;
    const int w     = tid >> 6;
    const int lane  = tid & 63;
    const int quad  = lane >> 4;
    const int lc    = lane & 15;
    const int n0    = qb * 256 + w * 64;

    __shared__ __align__(16) bf16 sK[2][64 * 64];
    __shared__ __align__(16) bf16 sV[2][64 * 64];
    __shared__ __align__(16) bf16 p_lds[4 * 16 * PSTR];
    bf16* pw = &p_lds[w * 16 * PSTR];

    const bf16* kbase = kTt + (((size_t)bh * 32 + c * 8) << 12);
    const bf16* vbase = vTt + (((size_t)bh * 32 + c * 8) << 12);

    // prologue: issue tile 0 -> buf 0 (each wave: 2KB of K + 2KB of V)
    #pragma unroll
    for (int j = 0; j < 2; ++j) {
        const int sseg = (w * 2 + j) << 9;          // 512-elem (1KB) segments
        gll16(kbase + sseg + lane * 8, &sK[0][sseg]);
        gll16(vbase + sseg + lane * 8, &sV[0][sseg]);
    }

    // Q fragments for 4 q-tiles (A layout)
    bf16x8 aq[4][2];
    #pragma unroll
    for (int t = 0; t < 4; ++t) {
        const bf16* qp = qT + ((size_t)bh * N_ + n0 + t * 16 + lc) * 64 + quad * 8;
        aq[t][0] = *(const bf16x8*)(qp);
        aq[t][1] = *(const bf16x8*)(qp + 32);
    }

    f32x4 accO[4][4];
    #pragma unroll
    for (int t = 0; t < 4; ++t)
        #pragma unroll
        for (int i = 0; i < 4; ++i) accO[t][i] = (f32x4){0.f, 0.f, 0.f, 0.f};
    float psum[4][4] = {{0.f,0.f,0.f,0.f},{0.f,0.f,0.f,0.f},
                        {0.f,0.f,0.f,0.f},{0.f,0.f,0.f,0.f}};

    const int rswz = (lc & 7) << 3;   // XOR swizzle matches producer layout

    for (int s = 0; s < 8; ++s) {
        const int buf = s & 1;
        // drains this wave's in-flight global_load_lds (vmcnt(0)) and joins
        // all waves: tile s fully resident in buf, everyone done with buf^1.
        __syncthreads();

        if (s < 7) {                   // prefetch tile s+1 into the other buf
            const bf16* kg = kbase + ((size_t)(s + 1) << 12);
            const bf16* vg = vbase + ((size_t)(s + 1) << 12);
            #pragma unroll
            for (int j = 0; j < 2; ++j) {
                const int sseg = (w * 2 + j) << 9;
                gll16(kg + sseg + lane * 8, &sK[buf ^ 1][sseg]);
                gll16(vg + sseg + lane * 8, &sV[buf ^ 1][sseg]);
            }
        }

        // fragments (shared by all 4 q-tiles)
        bf16x8 kf[4][2], vf[4][2];
        #pragma unroll
        for (int mt = 0; mt < 4; ++mt) {
            const int rb = (mt * 16 + lc) * 64;
            kf[mt][0] = *(const bf16x8*)&sK[buf][rb + ((quad * 8) ^ rswz)];
            kf[mt][1] = *(const bf16x8*)&sK[buf][rb + ((quad * 8 + 32) ^ rswz)];
            vf[mt][0] = *(const bf16x8*)&sV[buf][rb + ((quad * 8) ^ rswz)];
            vf[mt][1] = *(const bf16x8*)&sV[buf][rb + ((quad * 8 + 32) ^ rswz)];
        }

        #pragma unroll
        for (int t = 0; t < 4; ++t) {
            // ---- S ----
            f32x4 accS[4];
            #pragma unroll
            for (int mt = 0; mt < 4; ++mt) {
                f32x4 z = (f32x4){0.f, 0.f, 0.f, 0.f};
                z = __builtin_amdgcn_mfma_f32_16x16x32_bf16(aq[t][0], kf[mt][0], z, 0, 0, 0);
                z = __builtin_amdgcn_mfma_f32_16x16x32_bf16(aq[t][1], kf[mt][1], z, 0, 0, 0);
                accS[mt] = z;
            }
            // ---- P = exp2(S) (log2e folded into Q), per-lane partial sums ----
            #pragma unroll
            for (int r = 0; r < 4; ++r) {
                float sum = 0.f;
                #pragma unroll
                for (int mt = 0; mt < 4; ++mt) {
                    float p = fast_exp2(accS[mt][r]);
                    accS[mt][r] = p;
                    sum += p;
                }
                psum[t][r] += sum;
            }
            // ---- P -> LDS strip at permuted cols lc*4+mt: b64 writes ----
            #pragma unroll
            for (int r = 0; r < 4; ++r) {
                bf16x4 pk;
                #pragma unroll
                for (int mt = 0; mt < 4; ++mt) pk[mt] = (bf16)accS[mt][r];
                *(bf16x4*)&pw[(quad * 4 + r) * PSTR + lc * 4] = pk;
            }
            bf16x8 ap0 = *(const bf16x8*)(&pw[lc * PSTR + quad * 8]);
            bf16x8 ap1 = *(const bf16x8*)(&pw[lc * PSTR + 32 + quad * 8]);
            // ---- O += P * V^T (V pre-permuted to match) ----
            #pragma unroll
            for (int dvt = 0; dvt < 4; ++dvt) {
                accO[t][dvt] = __builtin_amdgcn_mfma_f32_16x16x32_bf16(ap0, vf[dvt][0], accO[t][dvt], 0, 0, 0);
                accO[t][dvt] = __builtin_amdgcn_mfma_f32_16x16x32_bf16(ap1, vf[dvt][1], accO[t][dvt], 0, 0, 0);
            }
        }
    }

    // ---- chunk denominators + chunk-normalized O ----
    #pragma unroll
    for (int t = 0; t < 4; ++t) {
        float inv_[4];
        #pragma unroll
        for (int r = 0; r < 4; ++r) {
            float s = psum[t][r];
            #pragma unroll
            for (int off = 1; off < 16; off <<= 1)
                s += __shfl_xor(s, off, 64);
            inv_[r] = 1.f / s;
            int n = n0 + t * 16 + quad * 4 + r;
            if (lc == 0)
                S_ws[((size_t)(c * B_ + b) * H_ + h) * N_ + n] = s;
        }
        #pragma unroll
        for (int r = 0; r < 4; ++r) {
            int n = n0 + t * 16 + quad * 4 + r;
            #pragma unroll
            for (int dvt = 0; dvt < 4; ++dvt) {
                int o = h * 64 + dvt * 16 + lc;
                Opart[((size_t)(c * B_ + b) * N_ + n) * 256 + o] = (bf16)(accO[t][dvt][r] * inv_[r]);
            }
        }
    }
}

// ---------------------------------------------------------------------------
// Kernel 3: skip GEMM (bf16 Wbf) + KS-chunk merge + permutation gather.
// Gather (inv -> S_ws/Opart) issued per-thread at kernel top so the two
// dependent global round-trips overlap staging + GEMM.
// grid (32 pos-tiles, 4 og(=h), B), 256 thr.
// ---------------------------------------------------------------------------
__global__ __launch_bounds__(256) void scatter_kernel(
    const bf16* __restrict__ Opart, const float* __restrict__ S_ws,
    const int* __restrict__ inv, const float* __restrict__ pcd,
    const bf16* __restrict__ Wbf, float* __restrict__ out)
{
    const int ptile = blockIdx.x;
    const int og    = blockIdx.y;     // == head h
    const int b     = blockIdx.z;
    const int tid   = threadIdx.x;
    const int w     = tid >> 6;
    const int lane  = tid & 63;
    const int quad  = lane >> 4;
    const int lc    = lane & 15;
    const int p0    = ptile * 64;

    __shared__ __align__(16) bf16 xT[64 * XSTR];    // pcd tile (dest order)
    __shared__ __align__(16) bf16 lds[64 * 72];     // merged attn [pos][o_loc]

    // --- early gather: issue the dependent inv -> S_ws/Opart chain now ---
    const int row0 = tid >> 3, seg = tid & 7, row1 = row0 + 32;
    int j0 = inv[b * N_ + p0 + row0] & (N_ - 1);
    int j1 = inv[b * N_ + p0 + row1] & (N_ - 1);
    float sv0[KS_], sv1[KS_];
    bf16x8 g0[KS_], g1[KS_];
    #pragma unroll
    for (int cc = 0; cc < KS_; ++cc) {
        g0[cc] = *(const bf16x8*)(Opart + (((size_t)(cc * B_ + b) * N_ + j0) << 8) + og * 64 + seg * 8);
        g1[cc] = *(const bf16x8*)(Opart + (((size_t)(cc * B_ + b) * N_ + j1) << 8) + og * 64 + seg * 8);
        sv0[cc] = S_ws[((size_t)(cc * B_ + b) * H_ + og) * N_ + j0];
        sv1[cc] = S_ws[((size_t)(cc * B_ + b) * H_ + og) * N_ + j1];
    }

    // stage pcd fp32 [c][pos] -> bf16 xT [pos][c^swz]
    const float* srcp = pcd + (size_t)b * C_IN_ * N_ + p0;
    #pragma unroll
    for (int k = 0; k < 4; ++k) {
        int e  = tid + k * 256;
        int cp = e >> 4, nq = e & 15;
        int c0 = cp * 2;
        float4 v0 = *(const float4*)(srcp + (size_t)c0 * N_ + nq * 4);
        float4 v1 = *(const float4*)(srcp + (size_t)(c0 + 1) * N_ + nq * 4);
        int cc = c0 ^ ((nq & 3) << 3);
        float a0[4] = {v0.x, v0.y, v0.z, v0.w};
        float a1[4] = {v1.x, v1.y, v1.z, v1.w};
        #pragma unroll
        for (int i = 0; i < 4; ++i) {
            int n = nq * 4 + i;
            bf16x2 t; t[0] = (bf16)a0[i]; t[1] = (bf16)a1[i];
            *(bf16x2*)&xT[n * XSTR + cc] = t;
        }
    }
    __syncthreads();

    // skip GEMM: rows og*64 + w*16 .. +15, cols p0..p0+63, K=128 (A=W bf16)
    const bf16* wbase = Wbf + (size_t)3 * 256 * 128 + (size_t)(og * 64 + w * 16) * 128;
    f32x4 acc[4];
    #pragma unroll
    for (int i = 0; i < 4; ++i) acc[i] = (f32x4){0.f, 0.f, 0.f, 0.f};
    #pragma unroll
    for (int kq = 0; kq < 4; ++kq) {
        bf16x8 A = *(const bf16x8*)(wbase + (size_t)lc * 128 + kq * 32 + quad * 8);
        #pragma unroll
        for (int nt = 0; nt < 4; ++nt) {
            int row = nt * 16 + lc;
            int col = (kq * 32 + quad * 8) ^ (((row >> 2) & 3) << 3);
            bf16x8 Bf = *(const bf16x8*)&xT[row * XSTR + col];
            acc[nt] = __builtin_amdgcn_mfma_f32_16x16x32_bf16(A, Bf, acc[nt], 0, 0, 0);
        }
    }

    // merge KS chunks into lds[pos][o_loc] (gather data already in regs)
    {
        float d0 = 0.f, d1 = 0.f;
        #pragma unroll
        for (int cc = 0; cc < KS_; ++cc) { d0 += sv0[cc]; d1 += sv1[cc]; }
        float id0 = 1.f / d0, id1 = 1.f / d1;
        float a8[8], b8[8];
        #pragma unroll
        for (int i = 0; i < 8; ++i) { a8[i] = 0.f; b8[i] = 0.f; }
        #pragma unroll
        for (int cc = 0; cc < KS_; ++cc) {
            float w0 = sv0[cc] * id0, w1 = sv1[cc] * id1;
            #pragma unroll
            for (int i = 0; i < 8; ++i) {
                a8[i] += w0 * (float)g0[cc][i];
                b8[i] += w1 * (float)g1[cc][i];
            }
        }
        bf16x8 o8, p8;
        #pragma unroll
        for (int i = 0; i < 8; ++i) { o8[i] = (bf16)a8[i]; p8[i] = (bf16)b8[i]; }
        *(bf16x8*)&lds[row0 * 72 + seg * 8] = o8;
        *(bf16x8*)&lds[row1 * 72 + seg * 8] = p8;
    }
    __syncthreads();

    // combine: out = skip(acc) + lds[pos][o_loc]
    #pragma unroll
    for (int nt = 0; nt < 4; ++nt) {
        #pragma unroll
        for (int r = 0; r < 4; ++r) {
            int o_loc = w * 16 + quad * 4 + r;
            int p     = nt * 16 + lc;
            float attn = (float)lds[p * 72 + o_loc];
            out[((size_t)b * 256 + og * 64 + o_loc) * N_ + p0 + p] = acc[nt][r] + attn;
        }
    }
}

// ---------------------------------------------------------------------------
extern "C" void kernel_launch(void* const* d_in, const int* in_sizes, int n_in,
                              void* d_out, int out_size, void* d_ws, size_t ws_size,
                              hipStream_t stream) {
    const float* pcd  = (const float*)d_in[0];
    const float* sel  = (const float*)d_in[1];
    const float* drop = (const float*)d_in[2];
    const int*   isel = (const int*)d_in[3];
    const int*   idrp = (const int*)d_in[4];
    const float* Wq   = (const float*)d_in[5];
    const float* Wk   = (const float*)d_in[6];
    const float* Wv   = (const float*)d_in[7];
    const float* Ws   = (const float*)d_in[8];
    float* out = (float*)d_out;

    const size_t MB = 1024 * 1024;
    // ws: qT 4 | kTt 4 | vTt 4 | Opart 16 | S_ws 512K | Wbf 256K | inv 32K
    char*  ws    = (char*)d_ws;
    bf16*  qT    = (bf16*)(ws);
    bf16*  kTt   = (bf16*)(ws + 4 * MB);
    bf16*  vTt   = (bf16*)(ws + 8 * MB);
    bf16*  Opart = (bf16*)(ws + 12 * MB);
    float* S_ws  = (float*)(ws + 28 * MB);
    bf16*  Wbf   = (bf16*)(ws + 28 * MB + 512 * 1024);
    int*   inv   = (int*)(ws + 28 * MB + 768 * 1024);

    prep_kernel<<<dim3(160), 256, 0, stream>>>(isel, idrp, Wq, Wk, Wv, Ws, inv, Wbf);
    qkv_mfma_kernel<<<dim3(32, 6, B_), 256, 0, stream>>>(sel, drop, Wbf,
                                                         qT, kTt, vTt);
    attn_kernel<<<dim3(16 * 8 * KS_), 256, 0, stream>>>(qT, kTt, vTt, Opart, S_ws);
    scatter_kernel<<<dim3(32, 4, B_), 256, 0, stream>>>(Opart, S_ws, inv, pcd, Wbf, out);
}